// Round 2
// baseline (150.501 us; speedup 1.0000x reference)
//
#include <hip/hip_runtime.h>
#include <stdint.h>

// ---------------- Threefry-2x32, 20 rounds (exactly JAX's) ----------------
__host__ __device__ inline void tf2x32(uint32_t k0, uint32_t k1,
                                       uint32_t x0, uint32_t x1,
                                       uint32_t& o0, uint32_t& o1) {
  uint32_t k2 = k0 ^ k1 ^ 0x1BD11BDAu;
#define TFR(r) { x0 += x1; x1 = (x1 << (r)) | (x1 >> (32 - (r))); x1 ^= x0; }
  x0 += k0; x1 += k1;
  TFR(13) TFR(15) TFR(26) TFR(6)  x0 += k1; x1 += k2 + 1u;
  TFR(17) TFR(29) TFR(16) TFR(24) x0 += k2; x1 += k0 + 2u;
  TFR(13) TFR(15) TFR(26) TFR(6)  x0 += k0; x1 += k1 + 3u;
  TFR(17) TFR(29) TFR(16) TFR(24) x0 += k1; x1 += k2 + 4u;
  TFR(13) TFR(15) TFR(26) TFR(6)  x0 += k2; x1 += k0 + 5u;
#undef TFR
  o0 = x0; o1 = x1;
}

// JAX partitionable random_bits (32-bit): bits[j] = o0 ^ o1 of threefry(key,(0,j))
__device__ inline uint32_t jax_bits32(uint32_t k0, uint32_t k1, uint32_t j) {
  uint32_t r0, r1;
  tf2x32(k0, k1, 0u, j, r0, r1);
  return r0 ^ r1;
}

// bits -> float in [0,1): (bits>>9)|0x3F800000 bitcast - 1.0 (JAX _uniform)
__device__ inline float bits_to_f01(uint32_t b) {
  return __uint_as_float((b >> 9) | 0x3F800000u) - 1.0f;
}

// XLA ErfInv32 (Giles polynomial), branchless coefficient select
__device__ inline float erfinv32(float x) {
  float w = -log1pf(-x * x);
  bool lt = w < 5.0f;
  float t = lt ? (w - 2.5f) : (sqrtf(w) - 3.0f);
  float p =      lt ?  2.81022636e-08f : -0.000200214257f;
  p = fmaf(p, t, lt ?  3.43273939e-07f :  0.000100950558f);
  p = fmaf(p, t, lt ? -3.5233877e-06f  :  0.00134934322f);
  p = fmaf(p, t, lt ? -4.39150654e-06f : -0.00367342844f);
  p = fmaf(p, t, lt ?  0.00021858087f  :  0.00573950773f);
  p = fmaf(p, t, lt ? -0.00125372503f  : -0.0076224613f);
  p = fmaf(p, t, lt ? -0.00417768164f  :  0.00943887047f);
  p = fmaf(p, t, lt ?  0.246640727f    :  1.00167406f);
  p = fmaf(p, t, lt ?  1.50140941f     :  2.83297682f);
  return p * x;
}

// jax.random.normal: u = f*(hi-lo)+lo with lo=nextafter(-1,0); (hi-lo) rounds to 2.0f
__device__ inline float normal_from_bits(uint32_t b) {
  const float lo = __uint_as_float(0xBF7FFFFFu);  // nextafter(-1.f, 0.f)
  float f = bits_to_f01(b);
  float u = fmaxf(lo, fmaf(f, 2.0f, lo));
  return 1.41421356237309515f * erfinv32(u);
}

// order-preserving float<->uint encode for atomicMin on floats (incl. negatives)
__device__ inline unsigned encf(float f) {
  unsigned u = __float_as_uint(f);
  return (u & 0x80000000u) ? ~u : (u | 0x80000000u);
}
__device__ inline float decf(unsigned u) {
  unsigned b = (u & 0x80000000u) ? (u & 0x7FFFFFFFu) : ~u;
  return __uint_as_float(b);
}

// ---------------- prep: per-pixel argmax over 80 class channels + global min
template <int N>
__global__ __launch_bounds__(256) void prep_kernel(const float* __restrict__ x,
                                                   int* __restrict__ midx,
                                                   unsigned* __restrict__ minEnc) {
  int n = blockIdx.x * 256 + threadIdx.x;
  float mn = INFINITY;
  if (n < N) {
    const float* p = x + 5 * N + n;   // batch 0, channel 5+k at offset k*N
    float best = -INFINITY;
    int bi = 0;
#pragma unroll 8
    for (int k = 0; k < 80; ++k) {
      float v = p[k * N];
      if (v > best) { best = v; bi = k; }   // strict '>' => first max (jnp.argmax)
      mn = fminf(mn, v);
    }
    midx[n] = bi;
  }
  unsigned u = encf(mn);
  for (int off = 32; off > 0; off >>= 1) {
    unsigned o = __shfl_down(u, (unsigned)off, 64);
    u = (o < u) ? o : u;
  }
  if ((threadIdx.x & 63) == 0) atomicMin(minEnc, u);
}

// ---------------- main: class scatter-replace (batch 0) + gaussian noise ----
// 4 consecutive-n elements per thread (same b,c since N % 4 == 0).
template <int N>
__global__ __launch_bounds__(256) void main_kernel(
    const float* __restrict__ x, float* __restrict__ out,
    const int* __restrict__ midx, const unsigned* __restrict__ minEnc,
    const float* __restrict__ valuep,
    uint32_t uk0, uint32_t uk1, uint32_t nk0, uint32_t nk1) {
  constexpr unsigned C = 85u;
  constexpr unsigned TOT = 8u * C * (unsigned)N;
  unsigned i0 = (blockIdx.x * 256u + threadIdx.x) * 4u;
  if (i0 >= TOT) return;
  unsigned n0 = i0 % (unsigned)N;
  unsigned bc = i0 / (unsigned)N;   // b*C + c
  unsigned c = bc % C;
  unsigned b = bc / C;

  float4 v = *reinterpret_cast<const float4*>(x + i0);
  float vv[4] = {v.x, v.y, v.z, v.w};

  if (b == 0u && c >= 5u) {
    unsigned k = c - 5u;
    float clsmin = decf(*minEnc);
#pragma unroll
    for (int q = 0; q < 4; ++q) {
      unsigned n = n0 + (unsigned)q;
      if ((unsigned)midx[n] != k) {
        // uniform array is [N, 80]: flat j = n*80 + k
        vv[q] = bits_to_f01(jax_bits32(uk0, uk1, n * 80u + k)) * clsmin;
      }
    }
  }

  // noise array is [B, N, C] (transposed layout): flat j = (b*N + n)*C + c
  float value = *valuep;
  unsigned jbase = (b * (unsigned)N + n0) * C + c;
#pragma unroll
  for (int q = 0; q < 4; ++q) {
    vv[q] += normal_from_bits(jax_bits32(nk0, nk1, jbase + C * (unsigned)q)) * value;
  }
  *reinterpret_cast<float4*>(out + i0) = make_float4(vv[0], vv[1], vv[2], vv[3]);
}

extern "C" void kernel_launch(void* const* d_in, const int* in_sizes, int n_in,
                              void* d_out, int out_size, void* d_ws, size_t ws_size,
                              hipStream_t stream) {
  const float* xs[3] = {(const float*)d_in[0], (const float*)d_in[1], (const float*)d_in[2]};
  const float* valuep = (const float*)d_in[3];
  float* out = (float*)d_out;

  const int Ns[3] = {160 * 160, 80 * 80, 40 * 40};

  // workspace layout: midx0 | midx1 | midx2 | mins[3]
  int* midx[3];
  midx[0] = (int*)d_ws;
  midx[1] = midx[0] + Ns[0];
  midx[2] = midx[1] + Ns[1];
  unsigned* mins = (unsigned*)(midx[2] + Ns[2]);

  hipMemsetAsync(mins, 0xFF, 3 * sizeof(unsigned), stream);

  // Host-side key derivation (partitionable threefry mode):
  //   base = key(42) = (0,42)
  //   key_i = fold_in(base, i) = threefry(base, (0,i))          [full pair]
  //   split(key_i) -> k1 = threefry(key_i,(0,0)), k2 = threefry(key_i,(0,1))
  uint32_t ku[3][2], kn[3][2];
  for (int i = 0; i < 3; ++i) {
    uint32_t f0, f1;
    tf2x32(0u, 42u, 0u, (uint32_t)i, f0, f1);
    tf2x32(f0, f1, 0u, 0u, ku[i][0], ku[i][1]);   // k1 -> uniform
    tf2x32(f0, f1, 0u, 1u, kn[i][0], kn[i][1]);   // k2 -> normal
  }

  float* outp = out;
  for (int i = 0; i < 3; ++i) {
    const int N = Ns[i];
    const int prep_blocks = (N + 255) / 256;
    const unsigned tot = 8u * 85u * (unsigned)N;
    const int main_blocks = (int)((tot / 4u + 255u) / 256u);
    switch (N) {
      case 25600:
        prep_kernel<25600><<<prep_blocks, 256, 0, stream>>>(xs[i], midx[i], mins + i);
        main_kernel<25600><<<main_blocks, 256, 0, stream>>>(
            xs[i], outp, midx[i], mins + i, valuep, ku[i][0], ku[i][1], kn[i][0], kn[i][1]);
        break;
      case 6400:
        prep_kernel<6400><<<prep_blocks, 256, 0, stream>>>(xs[i], midx[i], mins + i);
        main_kernel<6400><<<main_blocks, 256, 0, stream>>>(
            xs[i], outp, midx[i], mins + i, valuep, ku[i][0], ku[i][1], kn[i][0], kn[i][1]);
        break;
      case 1600:
        prep_kernel<1600><<<prep_blocks, 256, 0, stream>>>(xs[i], midx[i], mins + i);
        main_kernel<1600><<<main_blocks, 256, 0, stream>>>(
            xs[i], outp, midx[i], mins + i, valuep, ku[i][0], ku[i][1], kn[i][0], kn[i][1]);
        break;
      default:
        break;
    }
    outp += (size_t)8 * 85 * N;
  }
}

// Round 3
// 78.693 us; speedup vs baseline: 1.9125x; 1.9125x over previous
//
#include <hip/hip_runtime.h>
#include <stdint.h>

// ---------------- Threefry-2x32, 20 rounds (exactly JAX's) ----------------
__host__ __device__ inline void tf2x32(uint32_t k0, uint32_t k1,
                                       uint32_t x0, uint32_t x1,
                                       uint32_t& o0, uint32_t& o1) {
  uint32_t k2 = k0 ^ k1 ^ 0x1BD11BDAu;
#define TFR(r) { x0 += x1; x1 = (x1 << (r)) | (x1 >> (32 - (r))); x1 ^= x0; }
  x0 += k0; x1 += k1;
  TFR(13) TFR(15) TFR(26) TFR(6)  x0 += k1; x1 += k2 + 1u;
  TFR(17) TFR(29) TFR(16) TFR(24) x0 += k2; x1 += k0 + 2u;
  TFR(13) TFR(15) TFR(26) TFR(6)  x0 += k0; x1 += k1 + 3u;
  TFR(17) TFR(29) TFR(16) TFR(24) x0 += k1; x1 += k2 + 4u;
  TFR(13) TFR(15) TFR(26) TFR(6)  x0 += k2; x1 += k0 + 5u;
#undef TFR
  o0 = x0; o1 = x1;
}

// JAX partitionable random_bits (32-bit): bits[j] = o0 ^ o1 of threefry(key,(0,j))
__device__ inline uint32_t jax_bits32(uint32_t k0, uint32_t k1, uint32_t j) {
  uint32_t r0, r1;
  tf2x32(k0, k1, 0u, j, r0, r1);
  return r0 ^ r1;
}

// bits -> float in [0,1): (bits>>9)|0x3F800000 bitcast - 1.0 (JAX _uniform)
__device__ inline float bits_to_f01(uint32_t b) {
  return __uint_as_float((b >> 9) | 0x3F800000u) - 1.0f;
}

// sqrt(2)*erfinv via Giles polynomial, cheap transcendentals + real tail branch.
// Accuracy vs JAX's exact path ~1e-6 (log diff) — output budget is 0.108.
__device__ inline float normal_from_bits(uint32_t bits) {
  float f = __uint_as_float((bits >> 9) | 0x3F800000u) - 1.0f;
  const float lo = __uint_as_float(0xBF7FFFFFu);  // nextafter(-1.f, 0.f)
  float x = fmaxf(lo, fmaf(f, 2.0f, lo));
  float w = -__logf(fmaf(-x, x, 1.0f));           // -log(1-x^2), native v_log
  float z;
  if (w < 5.0f) {                                  // ~99.66% of lanes
    float t = w - 2.5f;
    float p =  2.81022636e-08f;
    p = fmaf(p, t,  3.43273939e-07f);
    p = fmaf(p, t, -3.5233877e-06f);
    p = fmaf(p, t, -4.39150654e-06f);
    p = fmaf(p, t,  0.00021858087f);
    p = fmaf(p, t, -0.00125372503f);
    p = fmaf(p, t, -0.00417768164f);
    p = fmaf(p, t,  0.246640727f);
    p = fmaf(p, t,  1.50140941f);
    z = p * x;
  } else {
    float t = __fsqrt_rn(w) - 3.0f;
    float p = -0.000200214257f;
    p = fmaf(p, t,  0.000100950558f);
    p = fmaf(p, t,  0.00134934322f);
    p = fmaf(p, t, -0.00367342844f);
    p = fmaf(p, t,  0.00573950773f);
    p = fmaf(p, t, -0.0076224613f);
    p = fmaf(p, t,  0.00943887047f);
    p = fmaf(p, t,  1.00167406f);
    p = fmaf(p, t,  2.83297682f);
    z = p * x;
  }
  return 1.41421356237309515f * z;
}

// order-preserving float<->uint encode for atomicMin on floats (incl. negatives)
__device__ inline unsigned encf(float f) {
  unsigned u = __float_as_uint(f);
  return (u & 0x80000000u) ? ~u : (u | 0x80000000u);
}
__device__ inline float decf(unsigned u) {
  unsigned b = (u & 0x80000000u) ? (u & 0x7FFFFFFFu) : ~u;
  return __uint_as_float(b);
}

// ---------------- fused prep: argmax over 80 class channels + per-tensor min
// block = 320 (5 waves); every wave is tensor-pure (all Ns divisible by 320).
__global__ __launch_bounds__(320) void prep_all(
    const float* __restrict__ x0, const float* __restrict__ x1,
    const float* __restrict__ x2, int* __restrict__ m0, int* __restrict__ m1,
    int* __restrict__ m2, unsigned* __restrict__ mins) {
  unsigned bid = blockIdx.x;
  const float* x; int* midx; unsigned* mE; unsigned N; unsigned lb;
  if (bid < 80u)       { x = x0; midx = m0; mE = mins;     N = 25600u; lb = bid; }
  else if (bid < 100u) { x = x1; midx = m1; mE = mins + 1; N = 6400u;  lb = bid - 80u; }
  else                 { x = x2; midx = m2; mE = mins + 2; N = 1600u;  lb = bid - 100u; }
  unsigned n = lb * 320u + threadIdx.x;
  const float* p = x + 5u * N + n;   // batch 0, channel 5+k at offset k*N
  float best = -INFINITY, mn = INFINITY;
  int bi = 0;
#pragma unroll 8
  for (int k = 0; k < 80; ++k) {
    float v = p[(unsigned)k * N];
    if (v > best) { best = v; bi = k; }   // strict '>' => first max (jnp.argmax)
    mn = fminf(mn, v);
  }
  midx[n] = bi;
  unsigned u = encf(mn);
  for (int off = 32; off > 0; off >>= 1) {
    unsigned o = __shfl_down(u, (unsigned)off, 64);
    u = (o < u) ? o : u;
  }
  if ((threadIdx.x & 63u) == 0u) atomicMin(mE, u);
}

// ---------------- fused main: scatter-replace (batch 0) + gaussian noise ----
struct TP {
  const float* x;
  float* out;
  const int* midx;
  uint32_t uk0, uk1, nk0, nk1;
  unsigned k;        // N = 25 << k
  unsigned N;
  unsigned tot;      // 680 * N
  unsigned blk_end;  // exclusive prefix sum of block counts
};

__global__ __launch_bounds__(256) void main_all(
    TP p0, TP p1, TP p2, const unsigned* __restrict__ mins,
    const float* __restrict__ valuep) {
  unsigned bid = blockIdx.x;
  TP P; unsigned t;
  if (bid < p0.blk_end)      { P = p0; t = 0u; }
  else if (bid < p1.blk_end) { P = p1; t = 1u; bid -= p0.blk_end; }
  else                       { P = p2; t = 2u; bid -= p1.blk_end; }

  unsigned i0 = (bid * 256u + threadIdx.x) * 4u;
  if (i0 >= P.tot) return;

  // bc = i0 / N via (i0 >> k) / 25 (magic);  b,c from bc < 680
  unsigned bc = __umulhi(i0 >> P.k, 0x51EB851Fu) >> 3;
  unsigned n0 = i0 - bc * P.N;
  unsigned b = (bc * 772u) >> 16;      // exact for bc < 680
  unsigned c = bc - b * 85u;

  float4 v = *reinterpret_cast<const float4*>(P.x + i0);
  float vv[4] = {v.x, v.y, v.z, v.w};

  if (b == 0u && c >= 5u) {
    unsigned kk = c - 5u;
    float clsmin = decf(mins[t]);
#pragma unroll
    for (int q = 0; q < 4; ++q) {
      unsigned n = n0 + (unsigned)q;
      if ((unsigned)P.midx[n] != kk) {
        // uniform array is [N, 80]: flat j = n*80 + kk
        vv[q] = bits_to_f01(jax_bits32(P.uk0, P.uk1, n * 80u + kk)) * clsmin;
      }
    }
  }

  // noise array is [B, N, C] (transposed layout): flat j = (b*N + n)*C + c
  float value = *valuep;
  unsigned jb = (b * P.N + n0) * 85u + c;
#pragma unroll
  for (int q = 0; q < 4; ++q) {
    vv[q] += normal_from_bits(jax_bits32(P.nk0, P.nk1, jb + 85u * (unsigned)q)) * value;
  }
  *reinterpret_cast<float4*>(P.out + i0) = make_float4(vv[0], vv[1], vv[2], vv[3]);
}

extern "C" void kernel_launch(void* const* d_in, const int* in_sizes, int n_in,
                              void* d_out, int out_size, void* d_ws, size_t ws_size,
                              hipStream_t stream) {
  const float* xs[3] = {(const float*)d_in[0], (const float*)d_in[1], (const float*)d_in[2]};
  const float* valuep = (const float*)d_in[3];
  float* out = (float*)d_out;

  const unsigned Ns[3] = {25600u, 6400u, 1600u};
  const unsigned ks[3] = {10u, 8u, 6u};   // N = 25 << k

  // workspace: midx0 | midx1 | midx2 | mins[3]
  int* midx[3];
  midx[0] = (int*)d_ws;
  midx[1] = midx[0] + Ns[0];
  midx[2] = midx[1] + Ns[1];
  unsigned* mins = (unsigned*)(midx[2] + Ns[2]);
  hipMemsetAsync(mins, 0xFF, 3 * sizeof(unsigned), stream);

  // Host-side key derivation (partitionable threefry):
  //   base = key(42) = (0,42); key_i = threefry(base,(0,i));
  //   split(key_i) -> k1 = threefry(key_i,(0,0)) [uniform], k2 = threefry(key_i,(0,1)) [normal]
  TP p[3];
  unsigned blk_acc = 0;
  float* outp = out;
  for (int i = 0; i < 3; ++i) {
    uint32_t f0, f1;
    tf2x32(0u, 42u, 0u, (uint32_t)i, f0, f1);
    tf2x32(f0, f1, 0u, 0u, p[i].uk0, p[i].uk1);
    tf2x32(f0, f1, 0u, 1u, p[i].nk0, p[i].nk1);
    p[i].x = xs[i];
    p[i].out = outp;
    p[i].midx = midx[i];
    p[i].k = ks[i];
    p[i].N = Ns[i];
    p[i].tot = 680u * Ns[i];
    blk_acc += (p[i].tot / 4u + 255u) / 256u;
    p[i].blk_end = blk_acc;
    outp += (size_t)680 * Ns[i];
  }

  prep_all<<<105, 320, 0, stream>>>(xs[0], xs[1], xs[2], midx[0], midx[1], midx[2], mins);
  main_all<<<blk_acc, 256, 0, stream>>>(p[0], p[1], p[2], mins, valuep);
}